// Round 5
// baseline (204.865 us; speedup 1.0000x reference)
//
#include <hip/hip_runtime.h>

#define B_  8
#define C_  256
#define O_  256
#define H_  56
#define W_  56
#define HW_ 3136
#define KK_ 9
#define CK_ 2304   // C_*KK_
#define NKC 72     // K-chunks of 32

typedef __bf16    bf16x8 __attribute__((ext_vector_type(8)));
typedef float     f32x4  __attribute__((ext_vector_type(4)));

// async 16B/lane global->LDS: lds base wave-uniform; HW adds lane*16.
__device__ __forceinline__ void async16(const void* gsrc_lane, void* lds_uniform) {
    __builtin_amdgcn_global_load_lds(
        (const __attribute__((address_space(1))) unsigned int*)gsrc_lane,
        (__attribute__((address_space(3))) unsigned int*)lds_uniform, 16, 0, 0);
}

// XOR chunk swizzle: logical 16B-chunk q of row r stored at q ^ swz4(r).
__device__ __forceinline__ int swz4(int r) { return (r & 3) ^ ((r >> 2) & 3); }

__device__ __forceinline__ float blo(unsigned u) {
    return __builtin_bit_cast(float, u << 16);
}
__device__ __forceinline__ float bhi(unsigned u) {
    return __builtin_bit_cast(float, u & 0xffff0000u);
}
__device__ __forceinline__ unsigned pkbf(float lo, float hi) {
    unsigned short a = __builtin_bit_cast(unsigned short, (__bf16)lo);
    unsigned short b = __builtin_bit_cast(unsigned short, (__bf16)hi);
    return (unsigned)a | ((unsigned)b << 16);
}

__device__ __forceinline__ uint2 bilin2(const uint2* c, float4 wg) {
    uint2 o;
    float lo_, hi_;
    lo_ = wg.x*blo(c[0].x) + wg.y*blo(c[1].x) + wg.z*blo(c[2].x) + wg.w*blo(c[3].x);
    hi_ = wg.x*bhi(c[0].x) + wg.y*bhi(c[1].x) + wg.z*bhi(c[2].x) + wg.w*bhi(c[3].x);
    o.x = pkbf(lo_, hi_);
    lo_ = wg.x*blo(c[0].y) + wg.y*blo(c[1].y) + wg.z*blo(c[2].y) + wg.w*blo(c[3].y);
    hi_ = wg.x*bhi(c[0].y) + wg.y*bhi(c[1].y) + wg.z*bhi(c[2].y) + wg.w*bhi(c[3].y);
    o.y = pkbf(lo_, hi_);
    return o;
}

// ---------------------------------------------------------------------------
// Kernel 1: wA[kc][m=256][32] bf16, tap-major K (gk=kc*32+kl -> tap=gk>>8,
// c=gk&255), XOR chunk swizzle baked into the global image. 1.18 MB.
// ---------------------------------------------------------------------------
__global__ __launch_bounds__(256) void k_buildA(const float* __restrict__ w,
                                                unsigned short* __restrict__ wA) {
    int d  = blockIdx.x * 256 + threadIdx.x;   // exact 2304*256
    int kc = d >> 13;
    int rd = d & 8191;
    int m  = rd >> 5;
    int pos = rd & 31;
    int q  = (pos >> 3) ^ swz4(m);
    int kl = q * 8 + (pos & 7);
    int gk = kc * 32 + kl;
    int tap = gk >> 8, c = gk & 255;
    __bf16 v = (__bf16)w[m * CK_ + c * KK_ + tap];
    wA[d] = __builtin_bit_cast(unsigned short, v);
}

// ---------------------------------------------------------------------------
// Kernel 2: x NCHW f32 -> xT NHWC bf16 (12.85 MB).
// ---------------------------------------------------------------------------
__global__ __launch_bounds__(256) void k_transx(const float* __restrict__ x,
                                                unsigned short* __restrict__ xT) {
    __shared__ float s[64][65];
    int bt   = blockIdx.x;            // 8 * 49 * 4
    int c64  = bt & 3;
    int hw64 = (bt >> 2) % 49;
    int b    = bt / 196;
    int tx = threadIdx.x & 63;
    int ty = threadIdx.x >> 6;
#pragma unroll
    for (int i = 0; i < 16; ++i)
        s[i * 4 + ty][tx] =
            x[((size_t)(b * 256 + c64 * 64 + i * 4 + ty)) * HW_ + hw64 * 64 + tx];
    __syncthreads();
#pragma unroll
    for (int i = 0; i < 16; ++i) {
        float v = s[tx][i * 4 + ty];
        xT[((size_t)b * HW_ + hw64 * 64 + i * 4 + ty) * 256 + c64 * 64 + tx] =
            __builtin_bit_cast(unsigned short, (__bf16)v);
    }
}

// ---------------------------------------------------------------------------
// Kernel 3a: offset conv partials. XCD-image swizzle keeps each image's x
// slice (3.2 MB) in one XCD's L2.
// ---------------------------------------------------------------------------
__global__ __launch_bounds__(512) void k_offc1(const float* __restrict__ x,
                                               const float* __restrict__ w_off,
                                               float* __restrict__ part) {
    __shared__ float partial[8][64][18];      // 36864 B
    int t  = threadIdx.x;
    int p  = t & 63;
    int cg = __builtin_amdgcn_readfirstlane(t >> 6);
    int orig = blockIdx.x;                    // 1568 = 8 XCD-chunks * 196
    int blk  = (orig & 7) * 196 + (orig >> 3);
    int sl   = blk & 3;
    int un   = blk >> 2;
    int b    = un / 49;
    int pos0 = (un % 49) * 64;
    int pos  = pos0 + p;
    int h = pos / W_;
    int w = pos % W_;
    const float* xb = x + (size_t)b * C_ * HW_;

    float acc[18];
#pragma unroll
    for (int i = 0; i < 18; ++i) acc[i] = 0.f;

    for (int cc = 0; cc < 8; ++cc) {
        int c = sl * 64 + cg * 8 + cc;
        const float* xp = xb + c * HW_;
        float v[9];
#pragma unroll
        for (int dh = -1; dh <= 1; ++dh)
#pragma unroll
            for (int dw = -1; dw <= 1; ++dw) {
                int hh = h + dh, ww = w + dw;
                bool ok = (hh >= 0) & (hh < H_) & (ww >= 0) & (ww < W_);
                v[(dh + 1) * 3 + dw + 1] = ok ? xp[hh * W_ + ww] : 0.f;
            }
        const float* wc = w_off + c * KK_;
#pragma unroll
        for (int oc = 0; oc < 18; ++oc) {
            const float* wr = wc + oc * CK_;  // wave-uniform -> s_load
#pragma unroll
            for (int k = 0; k < KK_; ++k)
                acc[oc] = fmaf(v[k], wr[k], acc[oc]);
        }
    }
#pragma unroll
    for (int oc = 0; oc < 18; ++oc) partial[cg][p][oc] = acc[oc];
    __syncthreads();

    float* po = part + (size_t)sl * (B_ * 18 * HW_);
    for (int e = t; e < 64 * 18; e += 512) {
        int oc = e >> 6;
        int pp = e & 63;
        float s = 0.f;
#pragma unroll
        for (int g = 0; g < 8; ++g) s += partial[g][pp][oc];
        po[((size_t)b * 18 + oc) * HW_ + pos0 + pp] = s;
    }
}

// ---------------------------------------------------------------------------
// Kernel 3b: sum 4 slices + bias -> off.
// ---------------------------------------------------------------------------
__global__ __launch_bounds__(256) void k_offc2(const float* __restrict__ part,
                                               const float* __restrict__ b_off,
                                               float* __restrict__ off) {
    int i = blockIdx.x * 256 + threadIdx.x;   // exact 451584
    const int NP = B_ * 18 * HW_;
    int oc = (i / HW_) % 18;
    off[i] = part[i] + part[i + NP] + part[i + 2 * NP] + part[i + 3 * NP]
           + b_off[oc];
}

// ---------------------------------------------------------------------------
// Kernel 4 (FUSED gather+GEMM), v4: same 256x64x32 stage tile + XCD-image
// swizzle as v3 (verified), but 8 waves (512 thr) and corner-register
// double-buffering.
//   - 8 waves = 4M x 2N, wave tile 64x32: 6 ds_read_b128 + 8 MFMA / stage.
//   - Corners for B(s+1) are issued at stage s-1 into one of two register
//     sets (parity-swapped) -> the L2 latency hides under a full stage.
//   - Per-thread per-stage VMEM: c(s+2)[4] + A(s+2)[2] async16.
//     vmcnt(12) at stage s drains exactly A(s) (newest 12 = c(s+1)4 +
//     A(s+1)2 + c(s+2)4 + A(s+2)2). Tail: 12/6/0. Never 0 mid-loop.
//   - id reloaded at i==6 (tap of c(s+2)); wg at i==7 (tap of B(s+1)).
// LDS: A 3x16K + B 2x4K + tables 18K = 74 KB -> 2 blocks/CU (16 waves).
// ---------------------------------------------------------------------------
template<int VM, bool ISSUEC, bool ISSUEA, bool PROD, bool RELID, bool RELWG>
__device__ __forceinline__ void fstage(
    int s, int chNext,
    const char* xb, const char* gA0,
    __bf16 (*s_a)[8192], __bf16 (*s_b)[1024 * 2],
    int (*s_id)[64][4], float (*s_w)[64][4],
    int4& id, float4& wg,
    uint2 (&cUse)[4], uint2 (&cFill)[4],
    int n, int tc, int wrsc, int wr, int wc, int lid, int quad, int swz,
    int wv, int lo, int parity, f32x4 (&acc)[4][2]) {

    if (RELID) {                        // table for tap of c(s+2)
        id = *(const int4*)s_id[(s + 2) >> 3][n];
    }
    if (RELWG) {                        // table for tap of B(s+1)
        wg = *(const float4*)s_w[(s + 1) >> 3][n];
    }
    if (ISSUEC) {                       // corners for stage s+2 (reg-staged)
        const char* p = xb + chNext * 64 + tc * 8;
        cFill[0] = *(const uint2*)(p + id.x);
        cFill[1] = *(const uint2*)(p + id.y);
        cFill[2] = *(const uint2*)(p + id.z);
        cFill[3] = *(const uint2*)(p + id.w);
    }
    if (ISSUEA) {                       // async A(s+2)
        const char* ga = gA0 + (size_t)(s + 2) * 16384;
        char* la = (char*)s_a[(s + 2) % 3];
#pragma unroll
        for (int j = 0; j < 2; ++j)
            async16(ga + wv * 2048 + j * 1024 + lo, la + wv * 2048 + j * 1024);
    }
    if (VM == 12)      asm volatile("s_waitcnt vmcnt(12)" ::: "memory");
    else if (VM == 6)  asm volatile("s_waitcnt vmcnt(6)"  ::: "memory");
    else               asm volatile("s_waitcnt vmcnt(0)"  ::: "memory");

    const bf16x8* pa = (const bf16x8*)s_a[s % 3];
    const bf16x8* pb = (const bf16x8*)s_b[s & 1];
    bf16x8 af[4], bv[2];
#pragma unroll
    for (int mi = 0; mi < 4; ++mi)
        af[mi] = pa[(wr * 64 + mi * 16 + lid) * 4 + (quad ^ swz)];
#pragma unroll
    for (int ni = 0; ni < 2; ++ni)
        bv[ni] = pb[(wc * 32 + ni * 16 + lid) * 4 + (quad ^ swz)];

    __builtin_amdgcn_s_setprio(1);
#pragma unroll
    for (int mi = 0; mi < 4; ++mi)
#pragma unroll
        for (int ni = 0; ni < 2; ++ni)
            acc[mi][ni] = __builtin_amdgcn_mfma_f32_16x16x32_bf16(
                af[mi], bv[ni], acc[mi][ni], 0, 0, 0);
    __builtin_amdgcn_s_setprio(0);

    if (PROD) {                         // B(s+1) from corners issued at s-1
        uint2 o = bilin2(cUse, wg);
        *(uint2*)((char*)s_b[(s & 1) ^ 1] + wrsc) = o;
    }
    asm volatile("s_waitcnt lgkmcnt(0)" ::: "memory");
    __builtin_amdgcn_s_barrier();
    __builtin_amdgcn_sched_barrier(0);
}

__global__ __launch_bounds__(512, 4) void k_fused(
    const unsigned short* __restrict__ xT,
    const float* __restrict__ off,
    const __bf16* __restrict__ wA,
    const float* __restrict__ b_dcn,
    float* __restrict__ out) {

    __shared__ __bf16 s_a[3][8192];       // 48 KB: A kc-tile 256m x 32k
    __shared__ __bf16 s_b[2][2048];       //  8 KB: B kc-tile  64n x 32k
    __shared__ int    s_id[KK_][64][4];   //  9 KB
    __shared__ float  s_w [KK_][64][4];   //  9 KB

    int bid  = blockIdx.x;                // 392 = 8 XCDs * 49
    int g    = (bid & 7) * 49 + (bid >> 3);   // image == XCD
    int b    = g / 49;
    int pos0 = (g % 49) * 64;
    int t    = threadIdx.x;
    int lane = t & 63;
    int wv   = t >> 6;                    // 8 waves
    int wr   = wv >> 1;                   // M-row of wave (4)
    int wc   = wv & 1;                    // N-col of wave (2)
    int lid  = lane & 15;
    int quad = lane >> 4;
    int swz  = swz4(lid);

    // --- bilinear tables (byte offsets into NHWC plane, 4 weights) ---
    for (int e = t; e < KK_ * 64; e += 512) {
        int k = e >> 6, n = e & 63;
        int pos = pos0 + n;
        int h = pos / W_, w = pos % W_;
        float dy = off[((size_t)b * 18 + 2 * k) * HW_ + pos];
        float dx = off[((size_t)b * 18 + 2 * k + 1) * HW_ + pos];
        float py = (float)(h + k / 3 - 1) + dy;
        float px = (float)(w + k % 3 - 1) + dx;
        float y0f = floorf(py), x0f = floorf(px);
        float fy = py - y0f, fx = px - x0f;
        int y0 = (int)y0f, x0 = (int)x0f;
        int y1 = y0 + 1,   x1 = x0 + 1;
        float oy0 = (y0 >= 0 && y0 < H_) ? 1.f : 0.f;
        float oy1 = (y1 >= 0 && y1 < H_) ? 1.f : 0.f;
        float ox0 = (x0 >= 0 && x0 < W_) ? 1.f : 0.f;
        float ox1 = (x1 >= 0 && x1 < W_) ? 1.f : 0.f;
        int y0c = min(max(y0, 0), H_ - 1), y1c = min(max(y1, 0), H_ - 1);
        int x0c = min(max(x0, 0), W_ - 1), x1c = min(max(x1, 0), W_ - 1);
        s_id[k][n][0] = (y0c * W_ + x0c) * 512;   // 256 ch * 2 B
        s_id[k][n][1] = (y0c * W_ + x1c) * 512;
        s_id[k][n][2] = (y1c * W_ + x0c) * 512;
        s_id[k][n][3] = (y1c * W_ + x1c) * 512;
        s_w[k][n][0] = (1.f - fy) * (1.f - fx) * oy0 * ox0;
        s_w[k][n][1] = (1.f - fy) * fx         * oy0 * ox1;
        s_w[k][n][2] = fy * (1.f - fx)         * oy1 * ox0;
        s_w[k][n][3] = fy * fx                 * oy1 * ox1;
    }
    __syncthreads();

    int n  = t >> 3;                      // 64 positions
    int tc = t & 7;                       // 8B chunk within 64B k-row
    int wrsc = n * 64 + (((tc >> 1) ^ swz4(n)) << 4) + (tc & 1) * 8;
    const char* xb  = (const char*)(xT + (size_t)b * HW_ * 256);
    const char* gA0 = (const char*)wA;
    int lo = lane * 16;

    f32x4 acc[4][2];
#pragma unroll
    for (int mi = 0; mi < 4; ++mi)
#pragma unroll
        for (int ni = 0; ni < 2; ++ni)
            acc[mi][ni] = (f32x4)(0.f);

    int4   id = *(const int4*)s_id[0][n];
    float4 wg = *(const float4*)s_w[0][n];
    uint2 cA[4], cB[4];

    // ---- prologue ----
    // order per thread: c(0)[4], A(0)[2], A(1)[2], <wait c0> bilinear B(0),
    // c(1)[4] -> outstanding entering stage 0: A0,A1,c1 = 8.
    {
        const char* p0 = xb + tc * 8;             // ch-block 0
        uint2 c0[4];
        c0[0] = *(const uint2*)(p0 + id.x);
        c0[1] = *(const uint2*)(p0 + id.y);
        c0[2] = *(const uint2*)(p0 + id.z);
        c0[3] = *(const uint2*)(p0 + id.w);
#pragma unroll
        for (int ss = 0; ss < 2; ++ss) {
            const char* ga = gA0 + (size_t)ss * 16384;
            char* la = (char*)s_a[ss];
#pragma unroll
            for (int j = 0; j < 2; ++j)
                async16(ga + wv * 2048 + j * 1024 + lo, la + wv * 2048 + j * 1024);
        }
        uint2 o = bilin2(c0, wg);
        *(uint2*)((char*)s_b[0] + wrsc) = o;
        const char* p1 = xb + 1 * 64 + tc * 8;    // corners(1), ch-block 1
        cA[0] = *(const uint2*)(p1 + id.x);
        cA[1] = *(const uint2*)(p1 + id.y);
        cA[2] = *(const uint2*)(p1 + id.z);
        cA[3] = *(const uint2*)(p1 + id.w);
    }
    asm volatile("s_waitcnt lgkmcnt(0)" ::: "memory");
    __builtin_amdgcn_s_barrier();
    __builtin_amdgcn_sched_barrier(0);

    // ---- main: 8 full tap-blocks (s = 0..63) ----
    // stage i uses cUse = set[i&1], fills set[(i+1)&1]
    for (int tap = 0; tap < 8; ++tap) {
        int s0 = tap * 8;
        fstage<12, true, true, true, false, false>(s0 + 0, 2, xb, gA0, s_a, s_b, s_id, s_w, id, wg, cA, cB, n, tc, wrsc, wr, wc, lid, quad, swz, wv, lo, 0, acc);
        fstage<12, true, true, true, false, false>(s0 + 1, 3, xb, gA0, s_a, s_b, s_id, s_w, id, wg, cB, cA, n, tc, wrsc, wr, wc, lid, quad, swz, wv, lo, 1, acc);
        fstage<12, true, true, true, false, false>(s0 + 2, 4, xb, gA0, s_a, s_b, s_id, s_w, id, wg, cA, cB, n, tc, wrsc, wr, wc, lid, quad, swz, wv, lo, 0, acc);
        fstage<12, true, true, true, false, false>(s0 + 3, 5, xb, gA0, s_a, s_b, s_id, s_w, id, wg, cB, cA, n, tc, wrsc, wr, wc, lid, quad, swz, wv, lo, 1, acc);
        fstage<12, true, true, true, false, false>(s0 + 4, 6, xb, gA0, s_a, s_b, s_id, s_w, id, wg, cA, cB, n, tc, wrsc, wr, wc, lid, quad, swz, wv, lo, 0, acc);
        fstage<12, true, true, true, false, false>(s0 + 5, 7, xb, gA0, s_a, s_b, s_id, s_w, id, wg, cB, cA, n, tc, wrsc, wr, wc, lid, quad, swz, wv, lo, 1, acc);
        fstage<12, true, true, true, true,  false>(s0 + 6, 0, xb, gA0, s_a, s_b, s_id, s_w, id, wg, cA, cB, n, tc, wrsc, wr, wc, lid, quad, swz, wv, lo, 0, acc);
        fstage<12, true, true, true, false, true >(s0 + 7, 1, xb, gA0, s_a, s_b, s_id, s_w, id, wg, cB, cA, n, tc, wrsc, wr, wc, lid, quad, swz, wv, lo, 1, acc);
    }
    // ---- tail tap-block (s = 64..71, tap 8) ----
    fstage<12, true,  true,  true,  false, false>(64, 2, xb, gA0, s_a, s_b, s_id, s_w, id, wg, cA, cB, n, tc, wrsc, wr, wc, lid, quad, swz, wv, lo, 0, acc);
    fstage<12, true,  true,  true,  false, false>(65, 3, xb, gA0, s_a, s_b, s_id, s_w, id, wg, cB, cA, n, tc, wrsc, wr, wc, lid, quad, swz, wv, lo, 1, acc);
    fstage<12, true,  true,  true,  false, false>(66, 4, xb, gA0, s_a, s_b, s_id, s_w, id, wg, cA, cB, n, tc, wrsc, wr, wc, lid, quad, swz, wv, lo, 0, acc);
    fstage<12, true,  true,  true,  false, false>(67, 5, xb, gA0, s_a, s_b, s_id, s_w, id, wg, cB, cA, n, tc, wrsc, wr, wc, lid, quad, swz, wv, lo, 1, acc);
    fstage<12, true,  true,  true,  false, false>(68, 6, xb, gA0, s_a, s_b, s_id, s_w, id, wg, cA, cB, n, tc, wrsc, wr, wc, lid, quad, swz, wv, lo, 0, acc);
    fstage<12, true,  true,  true,  false, false>(69, 7, xb, gA0, s_a, s_b, s_id, s_w, id, wg, cB, cA, n, tc, wrsc, wr, wc, lid, quad, swz, wv, lo, 1, acc);
    fstage<6,  false, false, true,  false, false>(70, 0, xb, gA0, s_a, s_b, s_id, s_w, id, wg, cA, cB, n, tc, wrsc, wr, wc, lid, quad, swz, wv, lo, 0, acc);
    fstage<0,  false, false, false, false, false>(71, 1, xb, gA0, s_a, s_b, s_id, s_w, id, wg, cB, cA, n, tc, wrsc, wr, wc, lid, quad, swz, wv, lo, 1, acc);

    // ---- epilogue: bias + store. D: col=lane&15, row(m)=quad*4+reg ----
#pragma unroll
    for (int mi = 0; mi < 4; ++mi) {
#pragma unroll
        for (int r = 0; r < 4; ++r) {
            int m = wr * 64 + mi * 16 + quad * 4 + r;
            float bias = b_dcn[m];
            float* po = out + ((size_t)b * O_ + m) * HW_ + pos0 + wc * 32 + lid;
#pragma unroll
            for (int ni = 0; ni < 2; ++ni)
                po[ni * 16] = acc[mi][ni][r] + bias;
        }
    }
}

extern "C" void kernel_launch(void* const* d_in, const int* in_sizes, int n_in,
                              void* d_out, int out_size, void* d_ws, size_t ws_size,
                              hipStream_t stream) {
    const float* x     = (const float*)d_in[0];
    const float* w_off = (const float*)d_in[1];
    const float* b_off = (const float*)d_in[2];
    const float* w_dcn = (const float*)d_in[3];
    const float* b_dcn = (const float*)d_in[4];
    float* out = (float*)d_out;

    // ws: off 1.81 | wA 1.18 | xT 12.85 | part 7.23 MB
    const size_t offBytes  = (size_t)451584 * 4;
    const size_t wABytes   = (size_t)589824 * 2;
    const size_t xTBytes   = (size_t)B_ * HW_ * 256 * 2;
    float*          off  = (float*)d_ws;
    unsigned short* wA   = (unsigned short*)((char*)d_ws + offBytes);
    unsigned short* xT   = (unsigned short*)((char*)d_ws + offBytes + wABytes);
    float*          part = (float*)((char*)d_ws + offBytes + wABytes + xTBytes);

    k_buildA <<<2304, 256, 0, stream>>>(w_dcn, wA);
    k_transx <<<1568, 256, 0, stream>>>(x, xT);
    k_offc1  <<<1568, 512, 0, stream>>>(x, w_off, part);
    k_offc2  <<<1764, 256, 0, stream>>>(part, b_off, off);
    k_fused  <<<392,  512, 0, stream>>>(xT, off, (const __bf16*)wA, b_dcn, out);
}